// Round 7
// baseline (418.099 us; speedup 1.0000x reference)
//
#include <hip/hip_runtime.h>

// SparseAttention on MI355X.
// R4: proj = fused fp32 SGEMM (Q+K in one launch, 4 blocks/CU, reg prefetch).
//     attn = 6-term bf16-split MFMA, 16 q-rows/block -> 2 blocks/CU.
//     Precision: proj stays fp32-exact (3-term split would flip ~25 thresholds);
//     QK^T 6-term split err ~2^-26 rel, below fp32 noise -> no flip risk.

#define THRESH 0.1f
#define PLANE (8 * 8 * 1024 * 64)   // elements per split plane [B][H][L][D]

typedef __attribute__((ext_vector_type(8))) short bf8_t;
typedef __attribute__((ext_vector_type(4))) float f4_t;

#define MFMA16(a, b, c) __builtin_amdgcn_mfma_f32_16x16x32_bf16(a, b, c, 0, 0, 0)

__device__ __forceinline__ unsigned short f2bf(float x) {  // RNE
  unsigned int u = __float_as_uint(x);
  u += 0x7FFFu + ((u >> 16) & 1u);
  return (unsigned short)(u >> 16);
}
__device__ __forceinline__ float bf2f(unsigned short h) {
  return __uint_as_float(((unsigned int)h) << 16);
}

// ---------------------------------------------------------------------------
// K1: fused projection GEMM (z=0: query@Wq^T+bq, z=1: key@Wk^T+bk).
// BM=128, BN=64, BK=16, 256 thr, micro 8x4. Grid (64, 8, 2) = 1024 blocks
// -> 4 blocks/CU. Next-tile regs prefetched before compute (loads span the
// compute phase). Epilogue emits 3 bf16 split planes [B][H][L][D].
// ---------------------------------------------------------------------------
__global__ __launch_bounds__(256) void proj_kernel(
    const float* __restrict__ query, const float* __restrict__ key,
    const float* __restrict__ Wq,    const float* __restrict__ Wk,
    const float* __restrict__ bq,    const float* __restrict__ bk,
    unsigned short* __restrict__ outq, unsigned short* __restrict__ outk)
{
  const int z = blockIdx.z;
  const float* A    = z ? key : query;
  const float* W    = z ? Wk  : Wq;
  const float* bias = z ? bk  : bq;
  unsigned short* outp = z ? outk : outq;

  __shared__ float As[16][132];
  __shared__ float Ws[16][68];
  const int t  = threadIdx.x;
  const int bm = blockIdx.x;     // 0..63
  const int bn = blockIdx.y;     // 0..7  (this block's head)
  const int ty = t >> 4;         // 0..15 -> 8 rows
  const int tx = t & 15;         // 0..15 -> 4 cols
  const int lr  = t >> 2;        // 0..63
  const int lc4 = (t & 3) << 2;  // 0,4,8,12

  const float* Arow0 = A + (size_t)(bm * 128 + lr) * 512 + lc4;
  const float* Arow1 = Arow0 + 64 * 512;
  const float* Wrow  = W + (size_t)(bn * 64 + lr) * 512 + lc4;

  float acc[8][4] = {};

  float4 a0 = *(const float4*)(Arow0);
  float4 a1 = *(const float4*)(Arow1);
  float4 w0 = *(const float4*)(Wrow);

  for (int k0 = 0; k0 < 512; k0 += 16) {
    __syncthreads();
    As[lc4 + 0][lr] = a0.x; As[lc4 + 1][lr] = a0.y; As[lc4 + 2][lr] = a0.z; As[lc4 + 3][lr] = a0.w;
    As[lc4 + 0][lr + 64] = a1.x; As[lc4 + 1][lr + 64] = a1.y; As[lc4 + 2][lr + 64] = a1.z; As[lc4 + 3][lr + 64] = a1.w;
    Ws[lc4 + 0][lr] = w0.x; Ws[lc4 + 1][lr] = w0.y; Ws[lc4 + 2][lr] = w0.z; Ws[lc4 + 3][lr] = w0.w;
    __syncthreads();
    if (k0 + 16 < 512) {       // prefetch next tile; loads fly over compute
      a0 = *(const float4*)(Arow0 + k0 + 16);
      a1 = *(const float4*)(Arow1 + k0 + 16);
      w0 = *(const float4*)(Wrow  + k0 + 16);
    }
    #pragma unroll
    for (int kk = 0; kk < 16; ++kk) {
      float4 av0 = *(const float4*)&As[kk][ty * 8];
      float4 av1 = *(const float4*)&As[kk][ty * 8 + 4];
      float4 bv0 = *(const float4*)&Ws[kk][tx * 4];
      float ar[8] = {av0.x, av0.y, av0.z, av0.w, av1.x, av1.y, av1.z, av1.w};
      float br[4] = {bv0.x, bv0.y, bv0.z, bv0.w};
      #pragma unroll
      for (int i = 0; i < 8; ++i)
        #pragma unroll
        for (int j = 0; j < 4; ++j)
          acc[i][j] += ar[i] * br[j];
    }
  }

  const int h = bn;
  #pragma unroll
  for (int i = 0; i < 8; ++i) {
    const int gr = bm * 128 + ty * 8 + i;
    const int l = gr >> 3;
    const int b = gr & 7;
    const int d = tx * 4;
    const size_t off = ((size_t)((b * 8 + h) * 1024 + l)) * 64 + d;
    ushort4 ph, pm, pl;
    #pragma unroll
    for (int q = 0; q < 4; ++q) {
      float x = acc[i][q] + bias[h * 64 + d + q];
      unsigned short b1 = f2bf(x);  float r1 = x  - bf2f(b1);
      unsigned short b2 = f2bf(r1); float r2 = r1 - bf2f(b2);
      unsigned short b3 = f2bf(r2);
      ((unsigned short*)&ph)[q] = b1;
      ((unsigned short*)&pm)[q] = b2;
      ((unsigned short*)&pl)[q] = b3;
    }
    *(ushort4*)&outp[off] = ph;
    *(ushort4*)&outp[(size_t)PLANE + off] = pm;
    *(ushort4*)&outp[(size_t)2 * PLANE + off] = pl;
  }
}

// ---------------------------------------------------------------------------
// K2: MFMA attention. Block = (b, 16 q-rows), 512 thr / 8 waves, grid 512
// (-> 2 blocks/CU; bx&7==b keeps same-b blocks on one XCD, K L2-resident).
// Wave w owns s-cols [w*128, w*128+128). 6-term split QK^T, cross-wave
// softmax via LDS, head-avg in regs, threshold+renorm epilogue -> sw[B][L][S].
// C/D layout (m89): col = lane&15, row = 4*(lane>>4) + reg.
// ---------------------------------------------------------------------------
__global__ __launch_bounds__(512, 2) void attn_mfma_kernel(
    const unsigned short* __restrict__ qs,  // 3 planes [B][H][L][64]
    const unsigned short* __restrict__ ks,  // 3 planes [B][H][S][64]
    float* __restrict__ sw)                 // [B][L][S]
{
  const int bx = blockIdx.x;
  const int b  = bx & 7;
  const int l0 = (bx >> 3) << 4;    // 16 q-rows
  const int tid  = threadIdx.x;
  const int w    = tid >> 6;
  const int lane = tid & 63;
  const int c    = lane & 15;
  const int g    = lane >> 4;

  __shared__ float red[8][16];
  __shared__ float redc[16];

  f4_t avg[8];
  #pragma unroll
  for (int ct = 0; ct < 8; ++ct) avg[ct] = (f4_t){0.f, 0.f, 0.f, 0.f};

  for (int h = 0; h < 8; ++h) {
    const size_t qbase = ((size_t)((b * 8 + h) * 1024 + l0)) * 64;
    const size_t kbase = ((size_t)((b * 8 + h) * 1024)) * 64;

    bf8_t qf[3][2];
    #pragma unroll
    for (int p = 0; p < 3; ++p)
      #pragma unroll
      for (int kc = 0; kc < 2; ++kc)
        qf[p][kc] = *(const bf8_t*)&qs[(size_t)p * PLANE + qbase +
                                       (size_t)c * 64 + kc * 32 + g * 8];

    f4_t acc[8];
    #pragma unroll
    for (int ct = 0; ct < 8; ++ct) acc[ct] = (f4_t){0.f, 0.f, 0.f, 0.f};

    #pragma unroll
    for (int ct = 0; ct < 8; ++ct) {
      const size_t kb = kbase + (size_t)(w * 128 + ct * 16 + c) * 64 + g * 8;
      #pragma unroll
      for (int kc = 0; kc < 2; ++kc) {
        bf8_t kh = *(const bf8_t*)&ks[kb + kc * 32];
        bf8_t km = *(const bf8_t*)&ks[(size_t)PLANE + kb + kc * 32];
        bf8_t kl = *(const bf8_t*)&ks[(size_t)2 * PLANE + kb + kc * 32];
        acc[ct] = MFMA16(qf[0][kc], kh, acc[ct]);  // hh
        acc[ct] = MFMA16(qf[0][kc], km, acc[ct]);  // hm
        acc[ct] = MFMA16(qf[1][kc], kh, acc[ct]);  // mh
        acc[ct] = MFMA16(qf[0][kc], kl, acc[ct]);  // hl
        acc[ct] = MFMA16(qf[1][kc], km, acc[ct]);  // mm
        acc[ct] = MFMA16(qf[2][kc], kh, acc[ct]);  // lh
      }
    }

    // ---- row max ----
    float mloc[4];
    #pragma unroll
    for (int reg = 0; reg < 4; ++reg) {
      float m = acc[0][reg];
      #pragma unroll
      for (int ct = 1; ct < 8; ++ct) m = fmaxf(m, acc[ct][reg]);
      #pragma unroll
      for (int off = 8; off > 0; off >>= 1) m = fmaxf(m, __shfl_xor(m, off));
      mloc[reg] = m;
    }
    if (c == 0) {
      #pragma unroll
      for (int reg = 0; reg < 4; ++reg) red[w][g * 4 + reg] = mloc[reg];
    }
    __syncthreads();
    if (tid < 16) {
      float m = red[0][tid];
      #pragma unroll
      for (int w2 = 1; w2 < 8; ++w2) m = fmaxf(m, red[w2][tid]);
      redc[tid] = m;
    }
    __syncthreads();
    float mrow[4];
    #pragma unroll
    for (int reg = 0; reg < 4; ++reg) mrow[reg] = redc[g * 4 + reg];

    // ---- exp + row sum ----
    float sloc[4] = {};
    #pragma unroll
    for (int ct = 0; ct < 8; ++ct)
      #pragma unroll
      for (int reg = 0; reg < 4; ++reg) {
        float p = __expf(0.125f * (acc[ct][reg] - mrow[reg]));
        acc[ct][reg] = p;
        sloc[reg] += p;
      }
    #pragma unroll
    for (int reg = 0; reg < 4; ++reg) {
      float s = sloc[reg];
      #pragma unroll
      for (int off = 8; off > 0; off >>= 1) s += __shfl_xor(s, off);
      sloc[reg] = s;
    }
    if (c == 0) {
      #pragma unroll
      for (int reg = 0; reg < 4; ++reg) red[w][g * 4 + reg] = sloc[reg];
    }
    __syncthreads();
    if (tid < 16) {
      float s = red[0][tid];
      #pragma unroll
      for (int w2 = 1; w2 < 8; ++w2) s += red[w2][tid];
      redc[tid] = s;
    }
    __syncthreads();
    #pragma unroll
    for (int reg = 0; reg < 4; ++reg) {
      const float inv = 0.125f / redc[g * 4 + reg];   // fold 1/H
      #pragma unroll
      for (int ct = 0; ct < 8; ++ct)
        avg[ct][reg] += acc[ct][reg] * inv;
    }
  }

  // ---- threshold + renormalize + store ----
  float tl[4] = {};
  #pragma unroll
  for (int ct = 0; ct < 8; ++ct)
    #pragma unroll
    for (int reg = 0; reg < 4; ++reg) {
      float v = avg[ct][reg];
      v = v > THRESH ? v : 0.f;
      avg[ct][reg] = v;
      tl[reg] += v;
    }
  #pragma unroll
  for (int reg = 0; reg < 4; ++reg) {
    float s = tl[reg];
    #pragma unroll
    for (int off = 8; off > 0; off >>= 1) s += __shfl_xor(s, off);
    tl[reg] = s;
  }
  if (c == 0) {
    #pragma unroll
    for (int reg = 0; reg < 4; ++reg) red[w][g * 4 + reg] = tl[reg];
  }
  __syncthreads();
  if (tid < 16) {
    float s = red[0][tid];
    #pragma unroll
    for (int w2 = 1; w2 < 8; ++w2) s += red[w2][tid];
    redc[tid] = s;
  }
  __syncthreads();
  #pragma unroll
  for (int reg = 0; reg < 4; ++reg) {
    const float inv = 1.f / (redc[g * 4 + reg] + 1e-6f);
    const size_t rowoff = ((size_t)(b * 1024 + l0 + g * 4 + reg)) * 1024;
    #pragma unroll
    for (int ct = 0; ct < 8; ++ct)
      sw[rowoff + w * 128 + ct * 16 + c] = avg[ct][reg] * inv;
  }
}

// ---------------------------------------------------------------------------
// K3: sparse PV (<=9 nnz/row guaranteed by threshold 0.1 + row-sum<=1).
// ---------------------------------------------------------------------------
__global__ __launch_bounds__(128) void pv_kernel(
    const float* __restrict__ sw,
    const float* __restrict__ value,
    float* __restrict__ out)
{
  const int l = blockIdx.x;
  const int b = blockIdx.y;
  const int t = threadIdx.x;
  __shared__ int cnt;
  __shared__ int   sidx[32];
  __shared__ float swt[32];
  if (t == 0) cnt = 0;
  __syncthreads();

  const float* row = sw + (size_t)(b * 1024 + l) * 1024;
  #pragma unroll
  for (int it = 0; it < 2; ++it) {
    const int s0 = (t + it * 128) * 4;
    float4 v = *(const float4*)(row + s0);
    if (v.x > 0.f) { int i = atomicAdd(&cnt, 1); if (i < 32) { sidx[i] = s0 + 0; swt[i] = v.x; } }
    if (v.y > 0.f) { int i = atomicAdd(&cnt, 1); if (i < 32) { sidx[i] = s0 + 1; swt[i] = v.y; } }
    if (v.z > 0.f) { int i = atomicAdd(&cnt, 1); if (i < 32) { sidx[i] = s0 + 2; swt[i] = v.z; } }
    if (v.w > 0.f) { int i = atomicAdd(&cnt, 1); if (i < 32) { sidx[i] = s0 + 3; swt[i] = v.w; } }
  }
  __syncthreads();
  const int n = cnt < 32 ? cnt : 32;

  const int e0 = t * 4;
  float4 o = {0.f, 0.f, 0.f, 0.f};
  for (int j = 0; j < n; ++j) {
    const float wgt = swt[j];
    const float4 vv = *(const float4*)(value + (size_t)(sidx[j] * 8 + b) * 512 + e0);
    o.x += wgt * vv.x; o.y += wgt * vv.y; o.z += wgt * vv.z; o.w += wgt * vv.w;
  }
  *(float4*)&out[(size_t)(l * 8 + b) * 512 + e0] = o;
}

// ---------------------------------------------------------------------------
extern "C" void kernel_launch(void* const* d_in, const int* in_sizes, int n_in,
                              void* d_out, int out_size, void* d_ws, size_t ws_size,
                              hipStream_t stream) {
  const float* query = (const float*)d_in[0];
  const float* key   = (const float*)d_in[1];
  const float* value = (const float*)d_in[2];
  const float* Wq    = (const float*)d_in[3];
  const float* bq    = (const float*)d_in[4];
  const float* Wk    = (const float*)d_in[5];
  const float* bk    = (const float*)d_in[6];

  float* out = (float*)d_out;
  float* sw  = out + (size_t)1024 * 8 * 512;

  unsigned short* qs = (unsigned short*)d_ws;          // 3 planes, 24 MB
  unsigned short* ks = qs + (size_t)3 * PLANE;         // 3 planes, 24 MB

  proj_kernel<<<dim3(64, 8, 2), 256, 0, stream>>>(query, key, Wq, Wk, bq, bk, qs, ks);
  attn_mfma_kernel<<<512, 512, 0, stream>>>(qs, ks, sw);
  pv_kernel<<<dim3(1024, 8), 128, 0, stream>>>(sw, value, out);
}

// Round 10
// 381.714 us; speedup vs baseline: 1.0953x; 1.0953x over previous
//
#include <hip/hip_runtime.h>

// SparseAttention on MI355X.
// R5: attn rebuilt for latency hiding: 32 q-rows/block (R3 reuse), explicit
// distance-2 K-fragment pipeline, Q-prefetch into dead regs over softmax,
// and lgkmcnt-only barriers (no vmcnt drain) so prefetch survives reductions.
// proj/pv unchanged from R4. 6-term bf16-split QK^T (fp32-equivalent).

#define THRESH 0.1f
#define PLANE (8 * 8 * 1024 * 64)   // elements per split plane [B][H][L][D]

typedef __attribute__((ext_vector_type(8))) short bf8_t;
typedef __attribute__((ext_vector_type(4))) float f4_t;

#define MFMA16(a, b, c) __builtin_amdgcn_mfma_f32_16x16x32_bf16(a, b, c, 0, 0, 0)

__device__ __forceinline__ unsigned short f2bf(float x) {  // RNE
  unsigned int u = __float_as_uint(x);
  u += 0x7FFFu + ((u >> 16) & 1u);
  return (unsigned short)(u >> 16);
}
__device__ __forceinline__ float bf2f(unsigned short h) {
  return __uint_as_float(((unsigned int)h) << 16);
}

// ---------------------------------------------------------------------------
// K1: fused projection GEMM (z=0: query@Wq^T+bq, z=1: key@Wk^T+bk).
// Unchanged from R4.
// ---------------------------------------------------------------------------
__global__ __launch_bounds__(256) void proj_kernel(
    const float* __restrict__ query, const float* __restrict__ key,
    const float* __restrict__ Wq,    const float* __restrict__ Wk,
    const float* __restrict__ bq,    const float* __restrict__ bk,
    unsigned short* __restrict__ outq, unsigned short* __restrict__ outk)
{
  const int z = blockIdx.z;
  const float* A    = z ? key : query;
  const float* W    = z ? Wk  : Wq;
  const float* bias = z ? bk  : bq;
  unsigned short* outp = z ? outk : outq;

  __shared__ float As[16][132];
  __shared__ float Ws[16][68];
  const int t  = threadIdx.x;
  const int bm = blockIdx.x;
  const int bn = blockIdx.y;
  const int ty = t >> 4;
  const int tx = t & 15;
  const int lr  = t >> 2;
  const int lc4 = (t & 3) << 2;

  const float* Arow0 = A + (size_t)(bm * 128 + lr) * 512 + lc4;
  const float* Arow1 = Arow0 + 64 * 512;
  const float* Wrow  = W + (size_t)(bn * 64 + lr) * 512 + lc4;

  float acc[8][4] = {};

  float4 a0 = *(const float4*)(Arow0);
  float4 a1 = *(const float4*)(Arow1);
  float4 w0 = *(const float4*)(Wrow);

  for (int k0 = 0; k0 < 512; k0 += 16) {
    __syncthreads();
    As[lc4 + 0][lr] = a0.x; As[lc4 + 1][lr] = a0.y; As[lc4 + 2][lr] = a0.z; As[lc4 + 3][lr] = a0.w;
    As[lc4 + 0][lr + 64] = a1.x; As[lc4 + 1][lr + 64] = a1.y; As[lc4 + 2][lr + 64] = a1.z; As[lc4 + 3][lr + 64] = a1.w;
    Ws[lc4 + 0][lr] = w0.x; Ws[lc4 + 1][lr] = w0.y; Ws[lc4 + 2][lr] = w0.z; Ws[lc4 + 3][lr] = w0.w;
    __syncthreads();
    if (k0 + 16 < 512) {
      a0 = *(const float4*)(Arow0 + k0 + 16);
      a1 = *(const float4*)(Arow1 + k0 + 16);
      w0 = *(const float4*)(Wrow  + k0 + 16);
    }
    #pragma unroll
    for (int kk = 0; kk < 16; ++kk) {
      float4 av0 = *(const float4*)&As[kk][ty * 8];
      float4 av1 = *(const float4*)&As[kk][ty * 8 + 4];
      float4 bv0 = *(const float4*)&Ws[kk][tx * 4];
      float ar[8] = {av0.x, av0.y, av0.z, av0.w, av1.x, av1.y, av1.z, av1.w};
      float br[4] = {bv0.x, bv0.y, bv0.z, bv0.w};
      #pragma unroll
      for (int i = 0; i < 8; ++i)
        #pragma unroll
        for (int j = 0; j < 4; ++j)
          acc[i][j] += ar[i] * br[j];
    }
  }

  const int h = bn;
  #pragma unroll
  for (int i = 0; i < 8; ++i) {
    const int gr = bm * 128 + ty * 8 + i;
    const int l = gr >> 3;
    const int b = gr & 7;
    const int d = tx * 4;
    const size_t off = ((size_t)((b * 8 + h) * 1024 + l)) * 64 + d;
    ushort4 ph, pm, pl;
    #pragma unroll
    for (int q = 0; q < 4; ++q) {
      float x = acc[i][q] + bias[h * 64 + d + q];
      unsigned short b1 = f2bf(x);  float r1 = x  - bf2f(b1);
      unsigned short b2 = f2bf(r1); float r2 = r1 - bf2f(b2);
      unsigned short b3 = f2bf(r2);
      ((unsigned short*)&ph)[q] = b1;
      ((unsigned short*)&pm)[q] = b2;
      ((unsigned short*)&pl)[q] = b3;
    }
    *(ushort4*)&outp[off] = ph;
    *(ushort4*)&outp[(size_t)PLANE + off] = pm;
    *(ushort4*)&outp[(size_t)2 * PLANE + off] = pl;
  }
}

// ---------------------------------------------------------------------------
// K2: MFMA attention, software-pipelined.
// Block = (b, 32 q-rows), grid 256 (b = bx&7 -> XCD-local K), 512 thr/8 waves.
// Wave w owns s-cols [w*128, +128). Unit u = ct*2+kc (16 units/head):
//   use kb[u&1] (3 planes), 12 MFMAs, prefetch unit u+2 (wraps into next head).
// Q fragments reloaded for h+1 after last use (hide under softmax).
// Softmax reduces: c==0 lanes write LDS, lgkmcnt-only barrier (no vmcnt
// drain!), all lanes broadcast-read-combine. Parity buffers per head.
// C/D layout (m89): col = lane&15, row = 4*(lane>>4) + reg.
// ---------------------------------------------------------------------------
__global__ __launch_bounds__(512, 1) void attn_mfma_kernel(
    const unsigned short* __restrict__ qs,  // 3 planes [B][H][L][64]
    const unsigned short* __restrict__ ks,  // 3 planes [B][H][S][64]
    float* __restrict__ sw)                 // [B][L][S]
{
  const int bx = blockIdx.x;
  const int b  = bx & 7;
  const int l0 = (bx >> 3) << 5;    // 32 q-rows
  const int tid  = threadIdx.x;
  const int w    = tid >> 6;
  const int lane = tid & 63;
  const int c    = lane & 15;
  const int g    = lane >> 4;

  __shared__ float mred[2][8][32];
  __shared__ float sred[2][8][32];

#define KADDR(H, CT, KC, PL) \
  ((const bf8_t*)&ks[(size_t)(PL) * PLANE + \
      ((size_t)((b * 8 + (H)) * 1024 + w * 128 + (CT) * 16 + c)) * 64 + (KC) * 32 + g * 8])
#define QADDR(H, RT, KC, PL) \
  ((const bf8_t*)&qs[(size_t)(PL) * PLANE + \
      ((size_t)((b * 8 + (H)) * 1024 + l0 + (RT) * 16 + c)) * 64 + (KC) * 32 + g * 8])

  f4_t avg[2][8];
  #pragma unroll
  for (int rt = 0; rt < 2; ++rt)
    #pragma unroll
    for (int ct = 0; ct < 8; ++ct)
      avg[rt][ct] = (f4_t){0.f, 0.f, 0.f, 0.f};

  bf8_t kb[2][3];        // rolling K buffers: kb[u&1][plane]
  bf8_t qf[3][2][2];     // [plane][rt][kc]

  // prologue: units 0,1 of head 0 + Q of head 0
  #pragma unroll
  for (int pl = 0; pl < 3; ++pl) {
    kb[0][pl] = *KADDR(0, 0, 0, pl);
    kb[1][pl] = *KADDR(0, 0, 1, pl);
    #pragma unroll
    for (int rt = 0; rt < 2; ++rt)
      #pragma unroll
      for (int kc = 0; kc < 2; ++kc)
        qf[pl][rt][kc] = *QADDR(0, rt, kc, pl);
  }

  for (int h = 0; h < 8; ++h) {
    const int par = h & 1;

    f4_t acc[2][8];
    #pragma unroll
    for (int rt = 0; rt < 2; ++rt)
      #pragma unroll
      for (int ct = 0; ct < 8; ++ct)
        acc[rt][ct] = (f4_t){0.f, 0.f, 0.f, 0.f};

    #pragma unroll
    for (int u = 0; u < 16; ++u) {
      const int ct = u >> 1, kc = u & 1, p = u & 1;
      const bf8_t kh = kb[p][0], km = kb[p][1], kl = kb[p][2];
      #pragma unroll
      for (int rt = 0; rt < 2; ++rt) {
        acc[rt][ct] = MFMA16(qf[0][rt][kc], kh, acc[rt][ct]);  // hh
        acc[rt][ct] = MFMA16(qf[0][rt][kc], km, acc[rt][ct]);  // hm
        acc[rt][ct] = MFMA16(qf[1][rt][kc], kh, acc[rt][ct]);  // mh
        acc[rt][ct] = MFMA16(qf[0][rt][kc], kl, acc[rt][ct]);  // hl
        acc[rt][ct] = MFMA16(qf[1][rt][kc], km, acc[rt][ct]);  // mm
        acc[rt][ct] = MFMA16(qf[2][rt][kc], kh, acc[rt][ct]);  // lh
      }
      // prefetch unit u+2 (crosses into next head at u=14,15)
      if (u + 2 < 16) {
        #pragma unroll
        for (int pl = 0; pl < 3; ++pl)
          kb[p][pl] = *KADDR(h, (u + 2) >> 1, (u + 2) & 1, pl);
      } else if (h < 7) {
        #pragma unroll
        for (int pl = 0; pl < 3; ++pl)
          kb[p][pl] = *KADDR(h + 1, (u - 14) >> 1, u & 1, pl);
      }
    }

    // qf is dead now: prefetch next head's Q (hides under softmax phase)
    if (h < 7) {
      #pragma unroll
      for (int pl = 0; pl < 3; ++pl)
        #pragma unroll
        for (int rt = 0; rt < 2; ++rt)
          #pragma unroll
          for (int kc = 0; kc < 2; ++kc)
            qf[pl][rt][kc] = *QADDR(h + 1, rt, kc, pl);
    }

    // ---- row max: local + wave shfl + 1 barrier + broadcast combine ----
    #pragma unroll
    for (int rt = 0; rt < 2; ++rt)
      #pragma unroll
      for (int reg = 0; reg < 4; ++reg) {
        float m = acc[rt][0][reg];
        #pragma unroll
        for (int ct = 1; ct < 8; ++ct) m = fmaxf(m, acc[rt][ct][reg]);
        #pragma unroll
        for (int off = 8; off > 0; off >>= 1) m = fmaxf(m, __shfl_xor(m, off));
        if (c == 0) mred[par][w][rt * 16 + g * 4 + reg] = m;
      }
    asm volatile("s_waitcnt lgkmcnt(0)\n\ts_barrier" ::: "memory");
    float mrow[2][4];
    #pragma unroll
    for (int rt = 0; rt < 2; ++rt) {
      float4 m4 = *(const float4*)&mred[par][0][rt * 16 + g * 4];
      #pragma unroll
      for (int w2 = 1; w2 < 8; ++w2) {
        float4 v = *(const float4*)&mred[par][w2][rt * 16 + g * 4];
        m4.x = fmaxf(m4.x, v.x); m4.y = fmaxf(m4.y, v.y);
        m4.z = fmaxf(m4.z, v.z); m4.w = fmaxf(m4.w, v.w);
      }
      mrow[rt][0] = m4.x; mrow[rt][1] = m4.y; mrow[rt][2] = m4.z; mrow[rt][3] = m4.w;
    }

    // ---- exp + row sum ----
    float sloc[2][4] = {};
    #pragma unroll
    for (int rt = 0; rt < 2; ++rt)
      #pragma unroll
      for (int ct = 0; ct < 8; ++ct)
        #pragma unroll
        for (int reg = 0; reg < 4; ++reg) {
          float p = __expf(0.125f * (acc[rt][ct][reg] - mrow[rt][reg]));
          acc[rt][ct][reg] = p;
          sloc[rt][reg] += p;
        }
    #pragma unroll
    for (int rt = 0; rt < 2; ++rt)
      #pragma unroll
      for (int reg = 0; reg < 4; ++reg) {
        float s = sloc[rt][reg];
        #pragma unroll
        for (int off = 8; off > 0; off >>= 1) s += __shfl_xor(s, off);
        if (c == 0) sred[par][w][rt * 16 + g * 4 + reg] = s;
      }
    asm volatile("s_waitcnt lgkmcnt(0)\n\ts_barrier" ::: "memory");
    #pragma unroll
    for (int rt = 0; rt < 2; ++rt) {
      float4 s4 = *(const float4*)&sred[par][0][rt * 16 + g * 4];
      #pragma unroll
      for (int w2 = 1; w2 < 8; ++w2) {
        float4 v = *(const float4*)&sred[par][w2][rt * 16 + g * 4];
        s4.x += v.x; s4.y += v.y; s4.z += v.z; s4.w += v.w;
      }
      float ssum[4] = {s4.x, s4.y, s4.z, s4.w};
      #pragma unroll
      for (int reg = 0; reg < 4; ++reg) {
        const float inv = 0.125f / ssum[reg];   // fold 1/H
        #pragma unroll
        for (int ct = 0; ct < 8; ++ct)
          avg[rt][ct][reg] += acc[rt][ct][reg] * inv;
      }
    }
  }

  // ---- threshold + renormalize + store ----
  float tl[2][4] = {};
  #pragma unroll
  for (int rt = 0; rt < 2; ++rt)
    #pragma unroll
    for (int ct = 0; ct < 8; ++ct)
      #pragma unroll
      for (int reg = 0; reg < 4; ++reg) {
        float v = avg[rt][ct][reg];
        v = v > THRESH ? v : 0.f;
        avg[rt][ct][reg] = v;
        tl[rt][reg] += v;
      }
  #pragma unroll
  for (int rt = 0; rt < 2; ++rt)
    #pragma unroll
    for (int reg = 0; reg < 4; ++reg) {
      float s = tl[rt][reg];
      #pragma unroll
      for (int off = 8; off > 0; off >>= 1) s += __shfl_xor(s, off);
      if (c == 0) mred[0][w][rt * 16 + g * 4 + reg] = s;
    }
  __syncthreads();
  #pragma unroll
  for (int rt = 0; rt < 2; ++rt) {
    float4 s4 = *(const float4*)&mred[0][0][rt * 16 + g * 4];
    #pragma unroll
    for (int w2 = 1; w2 < 8; ++w2) {
      float4 v = *(const float4*)&mred[0][w2][rt * 16 + g * 4];
      s4.x += v.x; s4.y += v.y; s4.z += v.z; s4.w += v.w;
    }
    float ts[4] = {s4.x, s4.y, s4.z, s4.w};
    #pragma unroll
    for (int reg = 0; reg < 4; ++reg) {
      const float inv = 1.f / (ts[reg] + 1e-6f);
      const size_t rowoff = ((size_t)(b * 1024 + l0 + rt * 16 + g * 4 + reg)) * 1024;
      #pragma unroll
      for (int ct = 0; ct < 8; ++ct)
        sw[rowoff + w * 128 + ct * 16 + c] = avg[rt][ct][reg] * inv;
    }
  }
#undef KADDR
#undef QADDR
}

// ---------------------------------------------------------------------------
// K3: sparse PV (<=9 nnz/row guaranteed by threshold 0.1 + row-sum<=1).
// ---------------------------------------------------------------------------
__global__ __launch_bounds__(128) void pv_kernel(
    const float* __restrict__ sw,
    const float* __restrict__ value,
    float* __restrict__ out)
{
  const int l = blockIdx.x;
  const int b = blockIdx.y;
  const int t = threadIdx.x;
  __shared__ int cnt;
  __shared__ int   sidx[32];
  __shared__ float swt[32];
  if (t == 0) cnt = 0;
  __syncthreads();

  const float* row = sw + (size_t)(b * 1024 + l) * 1024;
  #pragma unroll
  for (int it = 0; it < 2; ++it) {
    const int s0 = (t + it * 128) * 4;
    float4 v = *(const float4*)(row + s0);
    if (v.x > 0.f) { int i = atomicAdd(&cnt, 1); if (i < 32) { sidx[i] = s0 + 0; swt[i] = v.x; } }
    if (v.y > 0.f) { int i = atomicAdd(&cnt, 1); if (i < 32) { sidx[i] = s0 + 1; swt[i] = v.y; } }
    if (v.z > 0.f) { int i = atomicAdd(&cnt, 1); if (i < 32) { sidx[i] = s0 + 2; swt[i] = v.z; } }
    if (v.w > 0.f) { int i = atomicAdd(&cnt, 1); if (i < 32) { sidx[i] = s0 + 3; swt[i] = v.w; } }
  }
  __syncthreads();
  const int n = cnt < 32 ? cnt : 32;

  const int e0 = t * 4;
  float4 o = {0.f, 0.f, 0.f, 0.f};
  for (int j = 0; j < n; ++j) {
    const float wgt = swt[j];
    const float4 vv = *(const float4*)(value + (size_t)(sidx[j] * 8 + b) * 512 + e0);
    o.x += wgt * vv.x; o.y += wgt * vv.y; o.z += wgt * vv.z; o.w += wgt * vv.w;
  }
  *(float4*)&out[(size_t)(l * 8 + b) * 512 + e0] = o;
}

// ---------------------------------------------------------------------------
extern "C" void kernel_launch(void* const* d_in, const int* in_sizes, int n_in,
                              void* d_out, int out_size, void* d_ws, size_t ws_size,
                              hipStream_t stream) {
  const float* query = (const float*)d_in[0];
  const float* key   = (const float*)d_in[1];
  const float* value = (const float*)d_in[2];
  const float* Wq    = (const float*)d_in[3];
  const float* bq    = (const float*)d_in[4];
  const float* Wk    = (const float*)d_in[5];
  const float* bk    = (const float*)d_in[6];

  float* out = (float*)d_out;
  float* sw  = out + (size_t)1024 * 8 * 512;

  unsigned short* qs = (unsigned short*)d_ws;          // 3 planes, 24 MB
  unsigned short* ks = qs + (size_t)3 * PLANE;         // 3 planes, 24 MB

  proj_kernel<<<dim3(64, 8, 2), 256, 0, stream>>>(query, key, Wq, Wk, bq, bk, qs, ks);
  attn_mfma_kernel<<<256, 512, 0, stream>>>(qs, ks, sw);
  pv_kernel<<<dim3(1024, 8), 128, 0, stream>>>(sw, value, out);
}